// Round 14
// baseline (148.413 us; speedup 1.0000x reference)
//
#include <hip/hip_runtime.h>

#define SPK 1024
#define UTT 64
#define DIM 256
#define EPSV 1e-5f
#define NROW (SPK * UTT)
#define NSL 8            // column slices (128 cols each)
#define LOG2E 1.44269504f

typedef __attribute__((ext_vector_type(4))) float f32x4;    // MFMA accumulator
typedef __attribute__((ext_vector_type(2))) long long2v;    // 16 B = 2 fp8 ktile frags

#define EXP2(x) __builtin_amdgcn_exp2f(x)     // bare v_exp_f32, no libm guards

// pack 4 floats -> 4 fp8 e4m3 bytes
__device__ __forceinline__ int pk_fp8(float a, float b, float c, float d) {
    int v = __builtin_amdgcn_cvt_pk_fp8_f32(a, b, 0, false);   // bytes 0,1
    return  __builtin_amdgcn_cvt_pk_fp8_f32(c, d, v, true);    // bytes 2,3
}

// MFMA-fragment byte order for a 256-byte fp8 row/column:
// unit (r,quad) (16 B) = k-bytes [2r*32+quad*8 .. +8] ++ [(2r+1)*32+quad*8 .. +8].
// fragIdx maps original int-group g (bytes g*4..+4) -> stored int index.
__device__ __forceinline__ int fragIdx(int g) {
    return ((g >> 4) * 4 + ((g & 7) >> 1)) * 4 + ((g >> 3) & 1) * 2 + (g & 1);
}

// K1: one block (256 thr) per speaker. Phase A: csum + c_incl (fp8 x16,
// fragment order) + ||csum||^2. Phase B: 4 lanes per row (quad-reduce),
// x re-read L2-hot, writes e_n (fp8 x16, fragment order) and fp32 diagonal
// logit texcl = w*sim_excl + b.
__global__ __launch_bounds__(256)
void k_prep(const float* __restrict__ x,
            unsigned char* __restrict__ cincl8,
            unsigned char* __restrict__ en8,
            float* __restrict__ texcl,
            const float* __restrict__ wp, const float* __restrict__ bp) {
    __shared__ float4 sc4[256];
    __shared__ float4 cs4[64];
    __shared__ float sccs;
    int s = blockIdx.x, tid = threadIdx.x;
    int dq = tid & 63, ug = tid >> 6;
    const float4* x4 = (const float4*)(x + (size_t)s * UTT * DIM);

    // Phase A: column sums over the 64 utterances (coalesced 1KB/instr)
    float4 p = {0.f, 0.f, 0.f, 0.f};
#pragma unroll
    for (int i = 0; i < 16; ++i) {
        float4 v = x4[(ug * 16 + i) * 64 + dq];
        p.x += v.x; p.y += v.y; p.z += v.z; p.w += v.w;
    }
    sc4[tid] = p;
    __syncthreads();
    if (tid < 64) {
        float4 a = sc4[dq], b2 = sc4[64 + dq], c = sc4[128 + dq], d = sc4[192 + dq];
        float4 cs = {a.x + b2.x + c.x + d.x, a.y + b2.y + c.y + d.y,
                     a.z + b2.z + c.z + d.z, a.w + b2.w + c.w + d.w};
        cs4[dq] = cs;
        float s2 = cs.x * cs.x + cs.y * cs.y + cs.z * cs.z + cs.w * cs.w;
#pragma unroll
        for (int o = 1; o < 64; o <<= 1) s2 += __shfl_xor(s2, o);
        if (tid == 0) sccs = s2;
        // c_incl = csum/(||csum|| + U*eps), quantized x16 into e4m3
        float inv = 16.f / (sqrtf(s2) + UTT * EPSV);
        ((int*)cincl8)[s * 64 + fragIdx(dq)] =
            pk_fp8(cs.x * inv, cs.y * inv, cs.z * inv, cs.w * inv);
    }
    __syncthreads();
    float scc = sccs;
    float w = wp[0], b = bp[0];

    // Phase B: row = tid>>2 (64 rows), sub = tid&3 (4 lanes per row).
    int row = tid >> 2, sub = tid & 3;
    const float4* xr = x4 + row * 64;
    float4 xv[16];
    float sx = 0.f, sc = 0.f;
#pragma unroll
    for (int i = 0; i < 16; ++i) {
        float4 v = xr[i * 4 + sub];
        float4 cv = cs4[i * 4 + sub];
        xv[i] = v;
        sx += v.x * v.x + v.y * v.y + v.z * v.z + v.w * v.w;
        sc += v.x * cv.x + v.y * cv.y + v.z * cv.z + v.w * cv.w;
    }
    // quad reduce: all 4 lanes of the row end up with the totals
    sx += __shfl_xor(sx, 1); sx += __shfl_xor(sx, 2);
    sc += __shfl_xor(sc, 1); sc += __shfl_xor(sc, 2);
    float nx = sqrtf(sx);
    float inv = 16.f / (nx + EPSV);               // x16 into e4m3
    int* er = (int*)(en8 + (size_t)(s * UTT + row) * DIM);
#pragma unroll
    for (int i = 0; i < 16; ++i)
        er[fragIdx(i * 4 + sub)] = pk_fp8(xv[i].x * inv, xv[i].y * inv,
                                          xv[i].z * inv, xv[i].w * inv);
    if (sub == 0) {
        // sim_excl = x.(csum-x) / ((||x||+eps)(||csum-x||+63eps))  (fp32 exact)
        float num = sc - sx;
        float e2 = fmaxf(scc - 2.f * sc + sx, 0.f);
        float sim = num / ((nx + EPSV) * (sqrtf(e2) + (UTT - 1) * EPSV));
        texcl[s * UTT + row] = fmaf(sim, w, b);
    }
}

// K2: fp8 matmul, M=32 rows/wave for occupancy. Block = 2 speakers x 2
// row-halves (4 waves) x one 128-col slice; all waves share the 32 KB B
// slice (fragment-order LDS, zero-conflict ds_read_b128 at lane*16, one
// barrier per block). Small footprint (~100 regs: af2 32 + acc 16 + bf2 16)
// -> launch_bounds(256,4): 4 blocks/CU resident, so one wave's exp2
// epilogue overlaps another block's MFMA burst (the R13 latency fix).
// XCD swizzle keeps a speaker-pair's en8 slices on one XCD.
__global__ __launch_bounds__(256, 4)
void k_main(const unsigned char* __restrict__ en8,
            const unsigned char* __restrict__ cincl8,
            float* __restrict__ partial,
            const float* __restrict__ wp, const float* __restrict__ bp) {
    __shared__ unsigned char Bs[32 * 1024];      // 32 regions (nt,r) x 1 KB
    int tid = threadIdx.x, wave = tid >> 6, lane = tid & 63;
    int quad = lane >> 4, lx = lane & 15;
    int bid = blockIdx.x;
    int xcd = bid & 7, j = bid >> 3;             // j in [0,512)
    int cs = j & 7;                              // column slice (0..7)
    int sp = xcd + 8 * (j >> 3);                 // speaker pair (0..511)
    int sw = sp * 2 + (wave >> 1);               // this wave's speaker
    int rh = wave & 1;                           // row half (0..1)
    float w = wp[0], b = bp[0];
    float M  = fabsf(w) * 1.0625f + b;           // >= any logit (|sim| <= ~1)
    float wl = w * (LOG2E / 256.f);              // undo x16*x16 quant scale
    float bl = (b - M) * LOG2E;                  // exp(v-M) = exp2(acc*wl + bl)

    // stage B: region (nt,r) = 1 KB at (nt*4+r)*1024; lane ℓ supplies col
    // cs*128+nt*16+(ℓ&15), unit (r, ℓ>>4) -> LDS region + ℓ*16 (HW rule).
#pragma unroll
    for (int i = 0; i < 8; ++i) {
        int idx = wave * 8 + i;
        int nt = idx >> 2, r = idx & 3;
        const unsigned char* g = cincl8 +
            (size_t)(cs * 128 + nt * 16 + lx) * DIM + (r * 4 + quad) * 16;
        __builtin_amdgcn_global_load_lds(
            (const __attribute__((address_space(1))) void*)g,
            (__attribute__((address_space(3))) void*)(Bs + idx * 1024),
            16, 0, 0);
    }

    // A fragments (fragment-order rows): af2[mt][r] = ktiles (2r, 2r+1)
    const unsigned char* abase = en8 + (size_t)(sw * UTT + rh * 32) * DIM;
    long2v af2[2][4];
#pragma unroll
    for (int mt = 0; mt < 2; ++mt)
#pragma unroll
        for (int r = 0; r < 4; ++r)
            af2[mt][r] = *(const long2v*)(abase + (mt * 16 + lx) * DIM + (r * 4 + quad) * 16);

    float l[8];
#pragma unroll
    for (int i = 0; i < 8; ++i) l[i] = 0.f;

    __syncthreads();                             // staging complete (only barrier)

    int dnt = (sw >> 4) - cs * 8;                // diag ntile if in [0,8)
    int dlx = sw & 15;

    for (int nt = 0; nt < 8; ++nt) {
        long2v bf2[4];
#pragma unroll
        for (int r = 0; r < 4; ++r)
            bf2[r] = *(const long2v*)(Bs + (nt * 4 + r) * 1024 + lane * 16);
        f32x4 aA[2] = {{0.f,0.f,0.f,0.f},{0.f,0.f,0.f,0.f}};
        f32x4 aB[2] = {{0.f,0.f,0.f,0.f},{0.f,0.f,0.f,0.f}};
#pragma unroll
        for (int r = 0; r < 2; ++r) {            // 4 interleaved MFMA chains
#pragma unroll
            for (int mt = 0; mt < 2; ++mt) {
                aA[mt] = __builtin_amdgcn_mfma_f32_16x16x32_fp8_fp8(af2[mt][r].x,   bf2[r].x,   aA[mt], 0, 0, 0);
                aB[mt] = __builtin_amdgcn_mfma_f32_16x16x32_fp8_fp8(af2[mt][r+2].x, bf2[r+2].x, aB[mt], 0, 0, 0);
            }
#pragma unroll
            for (int mt = 0; mt < 2; ++mt) {
                aA[mt] = __builtin_amdgcn_mfma_f32_16x16x32_fp8_fp8(af2[mt][r].y,   bf2[r].y,   aA[mt], 0, 0, 0);
                aB[mt] = __builtin_amdgcn_mfma_f32_16x16x32_fp8_fp8(af2[mt][r+2].y, bf2[r+2].y, aB[mt], 0, 0, 0);
            }
        }
#pragma unroll
        for (int mt = 0; mt < 2; ++mt)
#pragma unroll
            for (int r = 0; r < 4; ++r)
                l[mt * 4 + r] += EXP2(fmaf(aA[mt][r] + aB[mt][r], wl, bl));
        if (nt == dnt) {                          // wave-uniform: undo diag col
#pragma unroll
            for (int mt = 0; mt < 2; ++mt)
#pragma unroll
                for (int r = 0; r < 4; ++r) {
                    float e = EXP2(fmaf(aA[mt][r] + aB[mt][r], wl, bl));
                    if (lx == dlx) l[mt * 4 + r] -= e;
                }
        }
    }

    // reduce over the 16 col-lanes; rows live at (quad, mt, r)
#pragma unroll
    for (int o = 1; o < 16; o <<= 1)
#pragma unroll
        for (int i = 0; i < 8; ++i) l[i] += __shfl_xor(l[i], o);
    if (lx == 0)
#pragma unroll
        for (int mt = 0; mt < 2; ++mt)
#pragma unroll
            for (int r = 0; r < 4; ++r)
                partial[(size_t)cs * NROW + (size_t)sw * UTT
                        + rh * 32 + mt * 16 + quad * 4 + r] = l[mt * 4 + r];
}

// K3: combine the 8 slice partials per row, logsumexp, mean-reduce.
__global__ __launch_bounds__(256)
void k_final(const float* __restrict__ partial, const float* __restrict__ texcl,
             const float* __restrict__ wp, const float* __restrict__ bp,
             float* __restrict__ out) {
    int row = blockIdx.x * 256 + threadIdx.x;
    float w = wp[0], b = bp[0];
    float M = fabsf(w) * 1.0625f + b;
    float t = 0.f;
#pragma unroll
    for (int sl = 0; sl < NSL; ++sl) t += partial[(size_t)sl * NROW + row];
    float tex = texcl[row];
    float c = (M + __logf(t + EXP2((tex - M) * LOG2E))) - tex;   // lse - target
#pragma unroll
    for (int o = 1; o < 64; o <<= 1) c += __shfl_xor(c, o);
    __shared__ float red[4];
    if ((threadIdx.x & 63) == 0) red[threadIdx.x >> 6] = c;
    __syncthreads();
    if (threadIdx.x == 0)
        atomicAdd(out, (red[0] + red[1] + red[2] + red[3]) * (1.f / NROW));
}

extern "C" void kernel_launch(void* const* d_in, const int* in_sizes, int n_in,
                              void* d_out, int out_size, void* d_ws, size_t ws_size,
                              hipStream_t stream) {
    const float* x  = (const float*)d_in[0];
    const float* wp = (const float*)d_in[1];
    const float* bp = (const float*)d_in[2];
    char* ws = (char*)d_ws;
    unsigned char* cincl8 = (unsigned char*)ws;                     // @0,    256 KB
    float* texcl          = (float*)(ws + (1u << 19));              // @512K, 256 KB
    float* partial        = (float*)(ws + (1u << 20));              // @1M,   2 MB
    unsigned char* en8    = (unsigned char*)(ws + (4u << 20));      // @4M,   16 MB
    float* out = (float*)d_out;

    hipMemsetAsync(d_out, 0, sizeof(float), stream);
    k_prep <<<SPK, 256, 0, stream>>>(x, cincl8, en8, texcl, wp, bp);
    k_main <<<(SPK / 2) * NSL, 256, 0, stream>>>(en8, cincl8, partial, wp, bp);
    k_final<<<NROW / 256, 256, 0, stream>>>(partial, texcl, wp, bp, out);
}